// Round 14
// baseline (74.359 us; speedup 1.0000x reference)
//
#include <hip/hip_runtime.h>
#include <hip/hip_bf16.h>
#include <cstdint>
#include <cstddef>

#define ALPHA 0.2f
#define LOG2E 1.4426950408889634f

using f32x4 = __attribute__((ext_vector_type(4))) float;
using s16x8 = __attribute__((ext_vector_type(8))) short;

typedef __attribute__((address_space(3))) unsigned lds_u32;
typedef __attribute__((address_space(1))) const unsigned glb_u32;

__device__ __forceinline__ unsigned f2bf(float f) {
  unsigned u = __float_as_uint(f);
  u = (u + 0x7fffu + ((u >> 16) & 1u)) >> 16;
  return u;
}

#define FENCE asm volatile("" ::: "memory")

// ---------------------------------------------------------------------------
// Kernel 1 (R12 version, verbatim; ~4.7 us by attribution)
// ---------------------------------------------------------------------------
__global__ __launch_bounds__(256) void k1_proj(
    const float* __restrict__ h, const float* __restrict__ W,
    const float* __restrict__ a1, const float* __restrict__ a2,
    unsigned short* __restrict__ whT, float* __restrict__ s1,
    float* __restrict__ s2) {
  __shared__ __align__(16) char h_lds[64 * 256];           // swizzled [n][k] f32
  __shared__ __align__(16) float W_lds[64 * 64];           // [k][c] linear
  __shared__ __align__(16) unsigned short t_lds[64 * 64];  // swizzled [c][n] bf16
  __shared__ float red[4][64][2];

  const int t = threadIdx.x;
  const int l = t & 63;
  const int w = t >> 6;
  const int rq = l & 15;            // row quad: rows rq*4 .. rq*4+3
  const int cq = w * 4 + (l >> 4);  // channel quad: c0 = cq*4
  const int c0 = cq * 4;
  const int row0 = blockIdx.x * 64;  // flat row base (b*2048 + n)

  const float4* hg = (const float4*)(h + (size_t)row0 * 64);
  #pragma unroll
  for (int r = 0; r < 4; ++r) {
    const int f = t + r * 256;  // 16B-chunk id, 0..1023
    const int n = f >> 4, ch = f & 15;
    *(float4*)(h_lds + n * 256 + ((ch * 16) ^ (((n >> 2) & 7) << 4))) = hg[f];
    ((float4*)W_lds)[f] = ((const float4*)W)[f];
  }
  const f32x4 a1v = *(const f32x4*)(a1 + c0);
  const f32x4 a2v = *(const f32x4*)(a2 + c0);
  __syncthreads();

  f32x4 acc[4];  // acc[i][j] = Wh[row0 + rq*4+i][c0+j]
  #pragma unroll
  for (int i = 0; i < 4; ++i) acc[i] = (f32x4){0.f, 0.f, 0.f, 0.f};

  #pragma unroll 1
  for (int kc = 0; kc < 16; ++kc) {
    f32x4 wv[4];  // wv[kk][j] = W[kc*4+kk][c0+j]
    #pragma unroll
    for (int kk = 0; kk < 4; ++kk)
      wv[kk] = *(const f32x4*)(W_lds + (kc * 4 + kk) * 64 + c0);
    #pragma unroll
    for (int i = 0; i < 4; ++i) {
      const int n = rq * 4 + i;
      const f32x4 hv = *(const f32x4*)(
          h_lds + n * 256 + ((kc * 16) ^ (((n >> 2) & 7) << 4)));
      #pragma unroll
      for (int j = 0; j < 4; ++j) {
        acc[i][j] = fmaf(hv[0], wv[0][j], acc[i][j]);
        acc[i][j] = fmaf(hv[1], wv[1][j], acc[i][j]);
        acc[i][j] = fmaf(hv[2], wv[2][j], acc[i][j]);
        acc[i][j] = fmaf(hv[3], wv[3][j], acc[i][j]);
      }
    }
  }

  float p1[4], p2[4];
  #pragma unroll
  for (int i = 0; i < 4; ++i) {
    p1[i] = acc[i][0] * a1v[0] + acc[i][1] * a1v[1] + acc[i][2] * a1v[2] +
            acc[i][3] * a1v[3];
    p2[i] = acc[i][0] * a2v[0] + acc[i][1] * a2v[1] + acc[i][2] * a2v[2] +
            acc[i][3] * a2v[3];
    p1[i] += __shfl_xor(p1[i], 16, 64);
    p1[i] += __shfl_xor(p1[i], 32, 64);
    p2[i] += __shfl_xor(p2[i], 16, 64);
    p2[i] += __shfl_xor(p2[i], 32, 64);
  }
  if (l < 16) {
    #pragma unroll
    for (int i = 0; i < 4; ++i) {
      red[w][rq * 4 + i][0] = p1[i];
      red[w][rq * 4 + i][1] = p2[i];
    }
  }

  #pragma unroll
  for (int j = 0; j < 4; ++j) {
    const int c = c0 + j;
    uint2 u;
    u.x = f2bf(acc[0][j]) | (f2bf(acc[1][j]) << 16);
    u.y = f2bf(acc[2][j]) | (f2bf(acc[3][j]) << 16);
    *(uint2*)((char*)t_lds + c * 128 + ((rq * 8) ^ ((c & 7) << 4))) = u;
  }
  __syncthreads();

  const int b = row0 >> 11;
  const int n0 = row0 & 2047;
  #pragma unroll
  for (int q = 0; q < 2; ++q) {
    const int chunk = q * 256 + t;
    const int cc = chunk >> 3;
    const int w8 = (chunk & 7) * 16;
    const uint4 v =
        *(const uint4*)((const char*)t_lds + cc * 128 + (w8 ^ ((cc & 7) << 4)));
    *(uint4*)((char*)whT + ((size_t)(b * 64 + cc) * 2048 + n0) * 2 + w8) = v;
  }
  if (t < 128) {
    const int n = t >> 1, v = t & 1;
    const float s =
        red[0][n][v] + red[1][n][v] + red[2][n][v] + red[3][n][v];
    if (v == 0)
      s1[row0 + n] = s;
    else
      s2[row0 + n] = s;
  }
}

// ---------------------------------------------------------------------------
// Kernel 2 R14: BARRIER-FREE final discriminator. R12/R13 plateau at 68us
// with all issue resources idle; R13 (2x waves, same per-iter barrier) was
// null, leaving the block-wide barrier convoy as the last untested lever.
// R14: per-wave PRIVATE 2-buffer whT (time-share: body(it) ds_reads
// buf[it&1], then post-MFMA -- after the compiler's lgkm waits prove reads
// complete -- issues gll(it+2) into the same buffer). No loop barrier at
// all; waves free-run. Cost: 4x whT traffic (L2-served, ~4us equiv).
// Bias 2-deep ping-pong. Per-wave vmcnt at the pre-MFMA wait: steady
// newer-than-gll(it) = {bias(it+1)4, gll(it+1)8, bias(it+2)4} = 16;
// tails 12 (it=30), 0 (it=31); prologue order bias(0),gll(0),gll(1),
// bias(1) matches. Unnormalized softmax (R11).
// ---------------------------------------------------------------------------
__global__ __launch_bounds__(256, 2) void k2_attn(
    const float* __restrict__ bias, const unsigned short* __restrict__ whT,
    const float* __restrict__ s1g, const float* __restrict__ s2g,
    float* __restrict__ out) {
  __shared__ __align__(16) unsigned short wvbuf[4][2][4096];  // private dbuf
  __shared__ __align__(16) float s2_lds[2048];

  const int t = threadIdx.x;
  const int lane = t & 63;
  const int w = t >> 6;
  const int arow = lane & 15;
  const int kgrp = lane >> 4;
  const int b = blockIdx.x >> 5;
  const int i0 = (blockIdx.x & 31) * 64;
  const int gi = i0 + w * 16 + arow;

  const float s1v = s1g[b * 2048 + gi];

  #pragma unroll
  for (int q = 0; q < 2; ++q)
    ((float4*)s2_lds)[t + q * 256] =
        ((const float4*)(s2g + b * 2048))[t + q * 256];
  __syncthreads();  // the ONLY barrier: s2_lds visibility

  const char* whT_b = (const char*)whT + (size_t)b * 64 * 2048 * 2;
  const float* bias_p = bias + ((size_t)b * 2048 + gi) * 2048 + kgrp * 8;

  // gll geometry (rule #21): linear LDS dest, inverse-swizzled global
  // source, swizzled ds_read. Private: 8 glls = full 8KB tile per wave.
  const int src_swz = ((lane & 7) * 16) ^ ((lane >> 3) << 4);
  const char* gsrc0 = whT_b + (size_t)(lane >> 3) * 4096 + src_swz;

  auto whT_gll = [&](int jt) {
    char* dst = (char*)wvbuf[w][jt & 1];
    #pragma unroll
    for (int q = 0; q < 8; ++q) {
      __builtin_amdgcn_global_load_lds(
          (glb_u32*)(gsrc0 + (size_t)q * 8 * 4096 + jt * 128),
          (lds_u32*)(dst + q * 1024), 16, 0, 0);
    }
  };
  auto bias_load = [&](f32x4 (&dst)[4], int jt) {
    const float* p = bias_p + jt * 64;
    dst[0] = *(const f32x4*)(p);
    dst[1] = *(const f32x4*)(p + 4);
    dst[2] = *(const f32x4*)(p + 32);
    dst[3] = *(const f32x4*)(p + 36);
  };

  f32x4 acc[4];
  #pragma unroll
  for (int ct = 0; ct < 4; ++ct) acc[ct] = (f32x4){0.f, 0.f, 0.f, 0.f};
  float l = 0.0f;

  f32x4 biasA[4], biasB[4];
  // prologue issue order: bias(0), gll(0), gll(1), bias(1)
  bias_load(biasA, 0);
  FENCE;
  whT_gll(0);
  whT_gll(1);
  FENCE;
  bias_load(biasB, 1);
  FENCE;

  auto body = [&](int jt, f32x4 (&bcur)[4], int vm) {
    // [B] p = exp2(log2e*(leakyrelu(s1+s2)+bias)); per-lane l; the compiler's
    // wait for bcur (bias(jt), issued 2 iters ago) is the only implicit wait.
    float ps = 0.0f;
    s16x8 afrag[2];
    #pragma unroll
    for (int f = 0; f < 2; ++f) {
      const f32x4 sa = *(const f32x4*)(s2_lds + jt * 64 + f * 32 + kgrp * 8);
      const f32x4 sb =
          *(const f32x4*)(s2_lds + jt * 64 + f * 32 + kgrp * 8 + 4);
      const f32x4 ba = bcur[f * 2 + 0];
      const f32x4 bb = bcur[f * 2 + 1];
      #pragma unroll
      for (int e = 0; e < 4; ++e) {
        float x = s1v + sa[e];
        x = fmaxf(x, ALPHA * x);  // leakyrelu
        const float p = exp2f((x + ba[e]) * LOG2E);
        ps += p;
        float y = s1v + sb[e];
        y = fmaxf(y, ALPHA * y);
        const float q = exp2f((y + bb[e]) * LOG2E);
        ps += q;
        afrag[f][e] = (short)f2bf(p);
        afrag[f][e + 4] = (short)f2bf(q);
      }
    }
    l += ps;

    // [A2] bias(jt+2) into the reg set just freed
    if (jt + 2 < 32) bias_load(bcur, jt + 2);
    FENCE;

    // [C] drain own gll(jt) (private; count derived in header comment)
    if (vm == 16)
      asm volatile("s_waitcnt vmcnt(16)" ::: "memory");
    else if (vm == 12)
      asm volatile("s_waitcnt vmcnt(12)" ::: "memory");
    else
      asm volatile("s_waitcnt vmcnt(0)" ::: "memory");

    // [E] PV MFMA from own buffer (no barrier -- private)
    const char* mybuf = (const char*)wvbuf[w][jt & 1];
    #pragma unroll
    for (int ct = 0; ct < 4; ++ct) {
      const int cc = ct * 16 + arow;
      #pragma unroll
      for (int f = 0; f < 2; ++f) {
        const s16x8 bfrag = *(const s16x8*)(
            mybuf + cc * 128 + ((f * 64 + kgrp * 16) ^ ((cc & 7) << 4)));
        asm("s_nop 1\n\t"
            "v_mfma_f32_16x16x32_bf16 %0, %1, %2, %0"
            : "+v"(acc[ct])
            : "v"(afrag[f]), "v"(bfrag));
      }
    }
    FENCE;
    // [F] prefetch whT(jt+2) into the buffer just fully read (same-wave:
    // compiler's lgkm waits before the MFMAs prove all bfrag reads complete)
    if (jt + 2 < 32) whT_gll(jt + 2);
    FENCE;
  };

  #pragma unroll 1
  for (int jt = 0; jt < 30; jt += 2) {
    body(jt + 0, biasA, 16);
    body(jt + 1, biasB, 16);
  }
  body(30, biasA, 12);
  body(31, biasB, 0);

  // MFMA-write -> VALU-read safety margin before epilogue reads of acc
  asm volatile("s_nop 7\n\ts_nop 7" ::: "memory");

  l += __shfl_xor(l, 16, 64);
  l += __shfl_xor(l, 32, 64);
  const float linv = 1.0f / l;
  #pragma unroll
  for (int r = 0; r < 4; ++r) {
    const float li = __shfl(linv, kgrp * 4 + r, 64);
    float* op = out + ((size_t)b * 2048 + i0 + w * 16 + kgrp * 4 + r) * 64;
    #pragma unroll
    for (int ct = 0; ct < 4; ++ct) op[ct * 16 + arow] = acc[ct][r] * li;
  }
}

// ---------------------------------------------------------------------------
extern "C" void kernel_launch(void* const* d_in, const int* in_sizes, int n_in,
                              void* d_out, int out_size, void* d_ws,
                              size_t ws_size, hipStream_t stream) {
  const float* h = (const float*)d_in[0];
  const float* bias = (const float*)d_in[1];
  const float* W = (const float*)d_in[2];
  const float* a1 = (const float*)d_in[3];
  const float* a2 = (const float*)d_in[4];
  float* out = (float*)d_out;

  char* ws = (char*)d_ws;
  unsigned short* whT = (unsigned short*)ws;                // 4 MiB
  float* s1 = (float*)(ws + 4 * 1024 * 1024);               // 128 KiB
  float* s2 = (float*)(ws + 4 * 1024 * 1024 + 128 * 1024);  // 128 KiB

  k1_proj<<<dim3(512), dim3(256), 0, stream>>>(h, W, a1, a2, whT, s1, s2);
  k2_attn<<<dim3(512), dim3(256), 0, stream>>>(bias, whT, s1, s2, out);
}

// Round 15
// 68.066 us; speedup vs baseline: 1.0924x; 1.0924x over previous
//
#include <hip/hip_runtime.h>
#include <hip/hip_bf16.h>
#include <cstdint>
#include <cstddef>

#define ALPHA 0.2f
#define LOG2E 1.4426950408889634f

using f32x4 = __attribute__((ext_vector_type(4))) float;
using s16x8 = __attribute__((ext_vector_type(8))) short;

typedef __attribute__((address_space(3))) unsigned lds_u32;
typedef __attribute__((address_space(1))) const unsigned glb_u32;

__device__ __forceinline__ unsigned f2bf(float f) {
  unsigned u = __float_as_uint(f);
  u = (u + 0x7fffu + ((u >> 16) & 1u)) >> 16;
  return u;
}

#define FENCE asm volatile("" ::: "memory")

// ---------------------------------------------------------------------------
// Kernel 1 (R12 version, verbatim; ~4.7 us by attribution). 4x4 register
// tiling; s1/s2 via per-thread 4-channel partials (16 shuffles + LDS pass).
// ---------------------------------------------------------------------------
__global__ __launch_bounds__(256) void k1_proj(
    const float* __restrict__ h, const float* __restrict__ W,
    const float* __restrict__ a1, const float* __restrict__ a2,
    unsigned short* __restrict__ whT, float* __restrict__ s1,
    float* __restrict__ s2) {
  __shared__ __align__(16) char h_lds[64 * 256];           // swizzled [n][k] f32
  __shared__ __align__(16) float W_lds[64 * 64];           // [k][c] linear
  __shared__ __align__(16) unsigned short t_lds[64 * 64];  // swizzled [c][n] bf16
  __shared__ float red[4][64][2];

  const int t = threadIdx.x;
  const int l = t & 63;
  const int w = t >> 6;
  const int rq = l & 15;            // row quad: rows rq*4 .. rq*4+3
  const int cq = w * 4 + (l >> 4);  // channel quad: c0 = cq*4
  const int c0 = cq * 4;
  const int row0 = blockIdx.x * 64;  // flat row base (b*2048 + n)

  const float4* hg = (const float4*)(h + (size_t)row0 * 64);
  #pragma unroll
  for (int r = 0; r < 4; ++r) {
    const int f = t + r * 256;  // 16B-chunk id, 0..1023
    const int n = f >> 4, ch = f & 15;
    *(float4*)(h_lds + n * 256 + ((ch * 16) ^ (((n >> 2) & 7) << 4))) = hg[f];
    ((float4*)W_lds)[f] = ((const float4*)W)[f];
  }
  const f32x4 a1v = *(const f32x4*)(a1 + c0);
  const f32x4 a2v = *(const f32x4*)(a2 + c0);
  __syncthreads();

  f32x4 acc[4];  // acc[i][j] = Wh[row0 + rq*4+i][c0+j]
  #pragma unroll
  for (int i = 0; i < 4; ++i) acc[i] = (f32x4){0.f, 0.f, 0.f, 0.f};

  #pragma unroll 1
  for (int kc = 0; kc < 16; ++kc) {
    f32x4 wv[4];  // wv[kk][j] = W[kc*4+kk][c0+j]
    #pragma unroll
    for (int kk = 0; kk < 4; ++kk)
      wv[kk] = *(const f32x4*)(W_lds + (kc * 4 + kk) * 64 + c0);
    #pragma unroll
    for (int i = 0; i < 4; ++i) {
      const int n = rq * 4 + i;
      const f32x4 hv = *(const f32x4*)(
          h_lds + n * 256 + ((kc * 16) ^ (((n >> 2) & 7) << 4)));
      #pragma unroll
      for (int j = 0; j < 4; ++j) {
        acc[i][j] = fmaf(hv[0], wv[0][j], acc[i][j]);
        acc[i][j] = fmaf(hv[1], wv[1][j], acc[i][j]);
        acc[i][j] = fmaf(hv[2], wv[2][j], acc[i][j]);
        acc[i][j] = fmaf(hv[3], wv[3][j], acc[i][j]);
      }
    }
  }

  float p1[4], p2[4];
  #pragma unroll
  for (int i = 0; i < 4; ++i) {
    p1[i] = acc[i][0] * a1v[0] + acc[i][1] * a1v[1] + acc[i][2] * a1v[2] +
            acc[i][3] * a1v[3];
    p2[i] = acc[i][0] * a2v[0] + acc[i][1] * a2v[1] + acc[i][2] * a2v[2] +
            acc[i][3] * a2v[3];
    p1[i] += __shfl_xor(p1[i], 16, 64);
    p1[i] += __shfl_xor(p1[i], 32, 64);
    p2[i] += __shfl_xor(p2[i], 16, 64);
    p2[i] += __shfl_xor(p2[i], 32, 64);
  }
  if (l < 16) {
    #pragma unroll
    for (int i = 0; i < 4; ++i) {
      red[w][rq * 4 + i][0] = p1[i];
      red[w][rq * 4 + i][1] = p2[i];
    }
  }

  #pragma unroll
  for (int j = 0; j < 4; ++j) {
    const int c = c0 + j;
    uint2 u;
    u.x = f2bf(acc[0][j]) | (f2bf(acc[1][j]) << 16);
    u.y = f2bf(acc[2][j]) | (f2bf(acc[3][j]) << 16);
    *(uint2*)((char*)t_lds + c * 128 + ((rq * 8) ^ ((c & 7) << 4))) = u;
  }
  __syncthreads();

  const int b = row0 >> 11;
  const int n0 = row0 & 2047;
  #pragma unroll
  for (int q = 0; q < 2; ++q) {
    const int chunk = q * 256 + t;
    const int cc = chunk >> 3;
    const int w8 = (chunk & 7) * 16;
    const uint4 v =
        *(const uint4*)((const char*)t_lds + cc * 128 + (w8 ^ ((cc & 7) << 4)));
    *(uint4*)((char*)whT + ((size_t)(b * 64 + cc) * 2048 + n0) * 2 + w8) = v;
  }
  if (t < 128) {
    const int n = t >> 1, v = t & 1;
    const float s =
        red[0][n][v] + red[1][n][v] + red[2][n][v] + red[3][n][v];
    if (v == 0)
      s1[row0 + n] = s;
    else
      s2[row0 + n] = s;
  }
}

// ---------------------------------------------------------------------------
// Kernel 2 (R11 version, verbatim; ~63.3 us by attribution — best of 6
// structural variants: 2-deep counted-vmcnt pipeline over a 4-slot shared
// whT ring + unnormalized softmax. R8/R9 (DRAM burst), R13 (2x occupancy),
// R14 (barrier-free) all null/negative -> delivered-BW-bound for this
// access shape (~4.4 TB/s sustained).
// ---------------------------------------------------------------------------
__global__ __launch_bounds__(256, 2) void k2_attn(
    const float* __restrict__ bias, const unsigned short* __restrict__ whT,
    const float* __restrict__ s1g, const float* __restrict__ s2g,
    float* __restrict__ out) {
  __shared__ __align__(16) unsigned short wbuf[4][4096];  // 4 x 8KB ring, swz
  __shared__ __align__(16) float s2_lds[2048];

  const int t = threadIdx.x;
  const int lane = t & 63;
  const int w = t >> 6;
  const int arow = lane & 15;  // softmax row within wave's 16
  const int kgrp = lane >> 4;  // 0..3
  const int b = blockIdx.x >> 5;
  const int i0 = (blockIdx.x & 31) * 64;
  const int gi = i0 + w * 16 + arow;

  const float s1v = s1g[b * 2048 + gi];

  #pragma unroll
  for (int q = 0; q < 2; ++q)
    ((float4*)s2_lds)[t + q * 256] =
        ((const float4*)(s2g + b * 2048))[t + q * 256];
  __syncthreads();  // s2_lds visibility (once, before the pipeline fills)

  const char* whT_b = (const char*)whT + (size_t)b * 64 * 2048 * 2;
  const float* bias_p = bias + ((size_t)b * 2048 + gi) * 2048 + kgrp * 8;

  // gll geometry (rule #21): linear LDS dest, inverse-swizzled global source,
  // swizzled ds_read. One gll moves 1KB = 8 whT rows x 128B. Wave w owns
  // chunks {2w, 2w+1} -> rows 16w..16w+15.
  const int src_swz = ((lane & 7) * 16) ^ ((lane >> 3) << 4);
  const char* gsrc0 = whT_b + (size_t)(lane >> 3) * 4096 + src_swz;

  auto whT_gll = [&](int jt) {
    char* dst = (char*)wbuf + (jt & 3) * 8192;
    #pragma unroll
    for (int q = 0; q < 2; ++q) {
      const int chunk = w * 2 + q;
      __builtin_amdgcn_global_load_lds(
          (glb_u32*)(gsrc0 + (size_t)chunk * 8 * 4096 + jt * 128),
          (lds_u32*)(dst + chunk * 1024), 16, 0, 0);
    }
  };
  auto bias_load = [&](f32x4 (&dst)[4], int jt) {
    const float* p = bias_p + jt * 64;
    dst[0] = *(const f32x4*)(p);
    dst[1] = *(const f32x4*)(p + 4);
    dst[2] = *(const f32x4*)(p + 32);
    dst[3] = *(const f32x4*)(p + 36);
  };

  f32x4 acc[4];
  #pragma unroll
  for (int ct = 0; ct < 4; ++ct) acc[ct] = (f32x4){0.f, 0.f, 0.f, 0.f};
  float l = 0.0f;  // per-lane partial denominator (16 j-slots per tile)

  f32x4 biasA[4], biasB[4];
  // prologue order: bias(0), gll(0), gll(1), bias(1) -- gll(k) older than
  // bias(k) so the compiler's bias(k)-read wait also drains gll(k).
  bias_load(biasA, 0);
  FENCE;
  whT_gll(0);
  whT_gll(1);
  FENCE;
  bias_load(biasB, 1);
  FENCE;

  auto body = [&](int jt, f32x4 (&bcur)[4]) {
    // [A] prefetch whT tile jt+2 -> buf[(jt+2)&3] (its readers, MFMA(jt-2),
    // finished two barriers ago)
    if (jt + 2 < 32) whT_gll(jt + 2);
    FENCE;

    // [B] p = exp2(log2e * (leakyrelu(s1_i + s2_j) + bias)); no max-sub
    // (bounded scores), no cross-lane ops. l accumulates per-lane.
    float ps = 0.0f;
    s16x8 afrag[2];
    #pragma unroll
    for (int f = 0; f < 2; ++f) {
      const f32x4 sa = *(const f32x4*)(s2_lds + jt * 64 + f * 32 + kgrp * 8);
      const f32x4 sb =
          *(const f32x4*)(s2_lds + jt * 64 + f * 32 + kgrp * 8 + 4);
      const f32x4 ba = bcur[f * 2 + 0];
      const f32x4 bb = bcur[f * 2 + 1];
      #pragma unroll
      for (int e = 0; e < 4; ++e) {
        float x = s1v + sa[e];
        x = fmaxf(x, ALPHA * x);  // leakyrelu
        const float p = exp2f((x + ba[e]) * LOG2E);
        ps += p;
        float y = s1v + sb[e];
        y = fmaxf(y, ALPHA * y);
        const float q = exp2f((y + bb[e]) * LOG2E);
        ps += q;
        afrag[f][e] = (short)f2bf(p);
        afrag[f][e + 4] = (short)f2bf(q);
      }
    }
    l += ps;

    // [A2] prefetch bias tile jt+2 into the reg set just freed by [B]
    if (jt + 2 < 32) bias_load(bcur, jt + 2);
    FENCE;

    // [C] drain own gll(jt): steady queue = {gll(jt+1), bias(jt+1),
    // gll(jt+2), bias(jt+2)} = 12 newer ops. Tail iters: compiler's
    // bias(jt)-read wait in [B] already drained gll(jt) (issue order).
    asm volatile("s_waitcnt vmcnt(12)" ::: "memory");
    // [D] all waves' gll(jt) drained -> buf[jt&3] fully valid
    asm volatile("s_barrier" ::: "memory");

    // [E] PV MFMA from the shared tile (unnormalized P)
    const char* mybuf = (const char*)wbuf + (jt & 3) * 8192;
    #pragma unroll
    for (int ct = 0; ct < 4; ++ct) {
      const int cc = ct * 16 + arow;
      #pragma unroll
      for (int f = 0; f < 2; ++f) {
        const s16x8 bfrag = *(const s16x8*)(
            mybuf + cc * 128 + ((f * 64 + kgrp * 16) ^ ((cc & 7) << 4)));
        asm("s_nop 1\n\t"
            "v_mfma_f32_16x16x32_bf16 %0, %1, %2, %0"
            : "+v"(acc[ct])
            : "v"(afrag[f]), "v"(bfrag));
      }
    }
  };

  #pragma unroll 1
  for (int jt = 0; jt < 32; jt += 2) {
    body(jt + 0, biasA);
    body(jt + 1, biasB);
  }

  // MFMA-write -> VALU-read safety margin before epilogue reads of acc
  asm volatile("s_nop 7\n\ts_nop 7" ::: "memory");

  // fold the 4 kgrp partials of each row, then normalize
  l += __shfl_xor(l, 16, 64);
  l += __shfl_xor(l, 32, 64);
  const float linv = 1.0f / l;
  #pragma unroll
  for (int r = 0; r < 4; ++r) {
    const float li = __shfl(linv, kgrp * 4 + r, 64);
    float* op = out + ((size_t)b * 2048 + i0 + w * 16 + kgrp * 4 + r) * 64;
    #pragma unroll
    for (int ct = 0; ct < 4; ++ct) op[ct * 16 + arow] = acc[ct][r] * li;
  }
}

// ---------------------------------------------------------------------------
extern "C" void kernel_launch(void* const* d_in, const int* in_sizes, int n_in,
                              void* d_out, int out_size, void* d_ws,
                              size_t ws_size, hipStream_t stream) {
  const float* h = (const float*)d_in[0];
  const float* bias = (const float*)d_in[1];
  const float* W = (const float*)d_in[2];
  const float* a1 = (const float*)d_in[3];
  const float* a2 = (const float*)d_in[4];
  float* out = (float*)d_out;

  char* ws = (char*)d_ws;
  unsigned short* whT = (unsigned short*)ws;                // 4 MiB
  float* s1 = (float*)(ws + 4 * 1024 * 1024);               // 128 KiB
  float* s2 = (float*)(ws + 4 * 1024 * 1024 + 128 * 1024);  // 128 KiB

  k1_proj<<<dim3(512), dim3(256), 0, stream>>>(h, W, a1, a2, whT, s1, s2);
  k2_attn<<<dim3(512), dim3(256), 0, stream>>>(bias, whT, s1, s2, out);
}